// Round 3
// baseline (503.766 us; speedup 1.0000x reference)
//
#include <hip/hip_runtime.h>
#include <stdint.h>

// Problem: B=4, S=2048, D_IN=1024, H=1024; fp32 in/out.
// Pipeline: [prep_mask] [split qkv->bf16 hi/lo] [split+transpose W]
//           [proj_qk GEMM split-bf16 -> Qhi/Qlo/Khi/Klo]
//           [proj_v GEMM plain bf16 -> Vt]
//           [scores GEMM split-bf16 *32 + maskbias -> fp32 scores]
//           [softmax in-place -> bf16 P]   [PV GEMM bf16 -> out]
// ws layout (needs ~156 MiB): mask | Whi|Wlo | Qhi|Qlo | Khi|Klo | Vt | A(->scores overlay)

#define S_LEN 2048
#define BATCH 4
#define DIN   1024
#define HDIM  1024
#define N3H   3072
#define NTOK  8192   // BATCH*S_LEN

typedef unsigned short u16;
typedef __attribute__((ext_vector_type(8))) short bf16x8;
typedef __attribute__((ext_vector_type(4))) float f32x4;
typedef __attribute__((ext_vector_type(4))) unsigned short u16x4;

// ---------- bf16 helpers (bit ops, RN) ----------
__device__ __forceinline__ u16 f2bf(float x) {
  union { float f; unsigned u; } c; c.f = x;
  unsigned r = c.u + 0x7fffu + ((c.u >> 16) & 1u);
  return (u16)(r >> 16);
}
__device__ __forceinline__ float bf2f(u16 h) {
  union { unsigned u; float f; } c; c.u = ((unsigned)h) << 16;
  return c.f;
}

// ---------- async global->LDS, width 16 ----------
__device__ __forceinline__ void gload16(const void* g, void* lds) {
  auto* gp = reinterpret_cast<const __attribute__((address_space(1))) void*>(
      reinterpret_cast<uintptr_t>(g));
  auto* lp = reinterpret_cast<__attribute__((address_space(3))) void*>(
      (unsigned)reinterpret_cast<uintptr_t>(lds));
  __builtin_amdgcn_global_load_lds(gp, lp, 16, 0, 0);
}

// Stage a 128x32 bf16 tile (row-major, row stride ld elems) into LDS (row-major [128][32]).
__device__ __forceinline__ void stage_tile(const u16* __restrict__ g, int ld,
                                           u16* lds, int wave, int lane) {
  const int rlane = lane >> 2;       // 0..15
  const int kofs  = (lane & 3) * 8;  // 0,8,16,24
#pragma unroll
  for (int h = 0; h < 2; ++h) {
    const int instr = wave * 2 + h;  // 0..7
    const u16* gp = g + (size_t)(instr * 16 + rlane) * ld + kofs;
    gload16(gp, (char*)lds + instr * 1024);
  }
}

// ---------- split-precision gemm_bt core: C(128x128) += (Ah+Al)*(Bh+Bl)^T ----------
// 3 MFMA products (hh, hl, lh); lo*lo dropped (2^-18 rel, negligible).
__device__ __forceinline__ void gemm_core_split(
    const u16* __restrict__ Ah, const u16* __restrict__ Al,
    const u16* __restrict__ Bh, const u16* __restrict__ Bl,
    int lda, int ldb, int K, f32x4 acc[4][4])
{
  __shared__ __align__(16) u16 lds[4 * 4096];  // aH | aL | bH | bL, 8KB each
  u16* aH = lds;          u16* aL = lds + 4096;
  u16* bH = lds + 8192;   u16* bL = lds + 12288;
  const int tid  = threadIdx.x;
  const int wave = tid >> 6, lane = tid & 63;
  const int wm = wave >> 1, wn = wave & 1;
  const int lrow = lane & 15, kq = lane >> 4;

  const f32x4 kZero = {0.f, 0.f, 0.f, 0.f};
#pragma unroll
  for (int i = 0; i < 4; ++i)
#pragma unroll
    for (int j = 0; j < 4; ++j) acc[i][j] = kZero;

  for (int k0 = 0; k0 < K; k0 += 32) {
    stage_tile(Ah + k0, lda, aH, wave, lane);
    stage_tile(Al + k0, lda, aL, wave, lane);
    stage_tile(Bh + k0, ldb, bH, wave, lane);
    stage_tile(Bl + k0, ldb, bL, wave, lane);
    __syncthreads();   // drains vmcnt (global_load_lds) before LDS reads

    bf16x8 fah[4], fal[4];
#pragma unroll
    for (int i = 0; i < 4; ++i) {
      const int off = (wm * 64 + i * 16 + lrow) * 32 + kq * 8;
      fah[i] = *(const bf16x8*)(aH + off);
      fal[i] = *(const bf16x8*)(aL + off);
    }
#pragma unroll
    for (int j = 0; j < 4; ++j) {
      const int off = (wn * 64 + j * 16 + lrow) * 32 + kq * 8;
      const bf16x8 fbh = *(const bf16x8*)(bH + off);
      const bf16x8 fbl = *(const bf16x8*)(bL + off);
#pragma unroll
      for (int i = 0; i < 4; ++i) {
        acc[i][j] = __builtin_amdgcn_mfma_f32_16x16x32_bf16(fah[i], fbh, acc[i][j], 0, 0, 0);
        acc[i][j] = __builtin_amdgcn_mfma_f32_16x16x32_bf16(fah[i], fbl, acc[i][j], 0, 0, 0);
        acc[i][j] = __builtin_amdgcn_mfma_f32_16x16x32_bf16(fal[i], fbh, acc[i][j], 0, 0, 0);
      }
    }
    __syncthreads();   // protect LDS before next stage
  }
}

// ---------- plain bf16 gemm_bt core ----------
__device__ __forceinline__ void gemm_core_plain(
    const u16* __restrict__ A, const u16* __restrict__ B,
    int lda, int ldb, int K, f32x4 acc[4][4])
{
  __shared__ __align__(16) u16 lds[2 * 4096];
  u16* aT = lds; u16* bT = lds + 4096;
  const int tid  = threadIdx.x;
  const int wave = tid >> 6, lane = tid & 63;
  const int wm = wave >> 1, wn = wave & 1;
  const int lrow = lane & 15, kq = lane >> 4;

  const f32x4 kZero = {0.f, 0.f, 0.f, 0.f};
#pragma unroll
  for (int i = 0; i < 4; ++i)
#pragma unroll
    for (int j = 0; j < 4; ++j) acc[i][j] = kZero;

  for (int k0 = 0; k0 < K; k0 += 32) {
    stage_tile(A + k0, lda, aT, wave, lane);
    stage_tile(B + k0, ldb, bT, wave, lane);
    __syncthreads();
    bf16x8 fa[4];
#pragma unroll
    for (int i = 0; i < 4; ++i) {
      const int off = (wm * 64 + i * 16 + lrow) * 32 + kq * 8;
      fa[i] = *(const bf16x8*)(aT + off);
    }
#pragma unroll
    for (int j = 0; j < 4; ++j) {
      const int off = (wn * 64 + j * 16 + lrow) * 32 + kq * 8;
      const bf16x8 fb = *(const bf16x8*)(bT + off);
#pragma unroll
      for (int i = 0; i < 4; ++i)
        acc[i][j] = __builtin_amdgcn_mfma_f32_16x16x32_bf16(fa[i], fb, acc[i][j], 0, 0, 0);
    }
    __syncthreads();
  }
}

// ---------- mask prep: detect bool(1B) vs int32(4B) repr, write additive bias ----------
__global__ void prep_mask_kernel(const unsigned char* __restrict__ m,
                                 float* __restrict__ bias) {
  __shared__ int isBool;
  if (threadIdx.x == 0) isBool = 0;
  __syncthreads();
  for (int i = threadIdx.x; i < NTOK; i += 256)
    if ((i & 3) && m[i]) isBool = 1;   // int32 repr of 0/1 has zero bytes at %4!=0
  __syncthreads();
  const int stride = isBool ? 1 : 4;
  const float ninf = -__builtin_inff();
  for (int i = threadIdx.x; i < NTOK; i += 256)
    bias[i] = m[(size_t)i * stride] ? ninf : 0.f;
}

// ---------- split fp32 -> bf16 hi/lo ----------
__global__ __launch_bounds__(256) void split_f32_kernel(
    const float* __restrict__ x, u16* __restrict__ hi, u16* __restrict__ lo) {
  const int i = (blockIdx.x * 256 + threadIdx.x) * 4;
  const f32x4 v = *(const f32x4*)(x + i);
  u16x4 h, l;
#pragma unroll
  for (int c = 0; c < 4; ++c) {
    h[c] = f2bf(v[c]);
    l[c] = f2bf(v[c] - bf2f(h[c]));
  }
  *(u16x4*)(hi + i) = h;
  *(u16x4*)(lo + i) = l;
}

// ---------- transpose + split W (DINxN3H -> N3HxDIN) ----------
__global__ __launch_bounds__(256) void splitWT_kernel(
    const float* __restrict__ W, u16* __restrict__ whi, u16* __restrict__ wlo) {
  const int o = blockIdx.x * 256 + threadIdx.x;  // o = n*DIN + d
  const int n = o >> 10, d = o & 1023;
  const float v = W[(size_t)d * N3H + n];
  const u16 h = f2bf(v);
  whi[o] = h;
  wlo[o] = f2bf(v - bf2f(h));
}

// ---------- projection GEMM (Q,K thirds): split precision ----------
__global__ __launch_bounds__(256, 4) void proj_qk_kernel(
    const u16* __restrict__ Ahi, const u16* __restrict__ Alo,
    const u16* __restrict__ Whi, const u16* __restrict__ Wlo,
    const float* __restrict__ bias,
    u16* __restrict__ qhi, u16* __restrict__ qlo,
    u16* __restrict__ khi, u16* __restrict__ klo)
{
  const int bx = blockIdx.x, by = blockIdx.y;  // bx over 16 tiles (cols 0..2047)
  f32x4 acc[4][4];
  gemm_core_split(Ahi + (size_t)by * 128 * DIN, Alo + (size_t)by * 128 * DIN,
                  Whi + (size_t)bx * 128 * DIN, Wlo + (size_t)bx * 128 * DIN,
                  DIN, DIN, DIN, acc);
  const int lane = threadIdx.x & 63, wave = threadIdx.x >> 6;
  const int wm = wave >> 1, wn = wave & 1;
#pragma unroll
  for (int i = 0; i < 4; ++i) {
#pragma unroll
    for (int r = 0; r < 4; ++r) {
      const int row = by * 128 + wm * 64 + i * 16 + (lane >> 4) * 4 + r;  // token
#pragma unroll
      for (int j = 0; j < 4; ++j) {
        const int col = bx * 128 + wn * 64 + j * 16 + (lane & 15);  // 0..2047
        const float v = acc[i][j][r] + bias[col];
        const u16 h = f2bf(v);
        const u16 l = f2bf(v - bf2f(h));
        if (col < HDIM) {                       // Q (block-uniform branch)
          const size_t idx = (size_t)row * HDIM + col;
          qhi[idx] = h; qlo[idx] = l;
        } else {                                // K
          const size_t idx = (size_t)row * HDIM + (col - HDIM);
          khi[idx] = h; klo[idx] = l;
        }
      }
    }
  }
}

// ---------- projection GEMM (V third): plain bf16, writes V transposed ----------
__global__ __launch_bounds__(256, 4) void proj_v_kernel(
    const u16* __restrict__ Ahi, const u16* __restrict__ Whi,
    const float* __restrict__ bias, u16* __restrict__ vt)
{
  const int bx = blockIdx.x, by = blockIdx.y;  // bx over 8 tiles (cols 2048..3071)
  f32x4 acc[4][4];
  gemm_core_plain(Ahi + (size_t)by * 128 * DIN,
                  Whi + (size_t)(2048 + bx * 128) * DIN,   // FIXED: was 16x too large
                  DIN, DIN, DIN, acc);
  const int lane = threadIdx.x & 63, wave = threadIdx.x >> 6;
  const int wm = wave >> 1, wn = wave & 1;
#pragma unroll
  for (int i = 0; i < 4; ++i) {
#pragma unroll
    for (int r = 0; r < 4; ++r) {
      const int row = by * 128 + wm * 64 + i * 16 + (lane >> 4) * 4 + r;  // token
      const int b = row >> 11, s = row & 2047;
#pragma unroll
      for (int j = 0; j < 4; ++j) {
        const int hcol = bx * 128 + wn * 64 + j * 16 + (lane & 15);  // 0..1023
        const float v = acc[i][j][r] + bias[2 * HDIM + hcol];
        vt[((size_t)b * HDIM + hcol) * S_LEN + s] = f2bf(v);
      }
    }
  }
}

// ---------- scores GEMM: sc = 32 * Q @ K^T + maskbias(key) ----------
__global__ __launch_bounds__(256, 4) void scores_kernel(
    const u16* __restrict__ qhi, const u16* __restrict__ qlo,
    const u16* __restrict__ khi, const u16* __restrict__ klo,
    const float* __restrict__ maskbias, float* __restrict__ scores)
{
  const int bx = blockIdx.x, by = blockIdx.y, b = blockIdx.z;
  f32x4 acc[4][4];
  const size_t qoff = ((size_t)b * S_LEN + by * 128) * HDIM;
  const size_t koff = ((size_t)b * S_LEN + bx * 128) * HDIM;
  gemm_core_split(qhi + qoff, qlo + qoff, khi + koff, klo + koff,
                  HDIM, HDIM, HDIM, acc);
  const int lane = threadIdx.x & 63, wave = threadIdx.x >> 6;
  const int wm = wave >> 1, wn = wave & 1;
#pragma unroll
  for (int i = 0; i < 4; ++i) {
#pragma unroll
    for (int r = 0; r < 4; ++r) {
      const int q = by * 128 + wm * 64 + i * 16 + (lane >> 4) * 4 + r;
#pragma unroll
      for (int j = 0; j < 4; ++j) {
        const int key = bx * 128 + wn * 64 + j * 16 + (lane & 15);
        scores[((size_t)b * S_LEN + q) * S_LEN + key] =
            32.0f * acc[i][j][r] + maskbias[b * S_LEN + key];
      }
    }
  }
}

// ---------- block reductions ----------
__device__ __forceinline__ float block_reduce_max(float v) {
#pragma unroll
  for (int o = 32; o > 0; o >>= 1) v = fmaxf(v, __shfl_down(v, o));
  __shared__ float tmp[4]; __shared__ float res;
  if ((threadIdx.x & 63) == 0) tmp[threadIdx.x >> 6] = v;
  __syncthreads();
  if (threadIdx.x == 0) res = fmaxf(fmaxf(tmp[0], tmp[1]), fmaxf(tmp[2], tmp[3]));
  __syncthreads();
  return res;
}
__device__ __forceinline__ float block_reduce_sum(float v) {
#pragma unroll
  for (int o = 32; o > 0; o >>= 1) v += __shfl_down(v, o);
  __shared__ float tmp[4]; __shared__ float res;
  if ((threadIdx.x & 63) == 0) tmp[threadIdx.x >> 6] = v;
  __syncthreads();
  if (threadIdx.x == 0) res = tmp[0] + tmp[1] + tmp[2] + tmp[3];
  __syncthreads();
  return res;
}

// ---------- softmax, in-place fp32 row -> bf16 P (row stride stays 8KB) ----------
__global__ __launch_bounds__(256) void softmax_kernel(float* __restrict__ scores) {
  const int row = blockIdx.x;              // 0..NTOK-1
  float* srow = scores + (size_t)row * S_LEN;
  const int t = threadIdx.x;
  const f32x4 v0 = ((const f32x4*)srow)[t];        // elems 4t..4t+3
  const f32x4 v1 = ((const f32x4*)srow)[256 + t];  // elems 1024+4t..

  float m = fmaxf(fmaxf(v0[0], v0[1]), fmaxf(v0[2], v0[3]));
  m = fmaxf(m, fmaxf(fmaxf(v1[0], v1[1]), fmaxf(v1[2], v1[3])));
  const float rowmax = block_reduce_max(m);

  float e[8];
#pragma unroll
  for (int c = 0; c < 4; ++c) e[c]     = expf(v0[c] - rowmax);
#pragma unroll
  for (int c = 0; c < 4; ++c) e[4 + c] = expf(v1[c] - rowmax);
  float s = 0.f;
#pragma unroll
  for (int c = 0; c < 8; ++c) s += e[c];
  const float inv = 1.0f / block_reduce_sum(s);

  u16* prow = (u16*)srow;   // bf16 row at same base; valid elems 0..2047, stride 4096
  u16x4 o0 = { f2bf(e[0] * inv), f2bf(e[1] * inv), f2bf(e[2] * inv), f2bf(e[3] * inv) };
  u16x4 o1 = { f2bf(e[4] * inv), f2bf(e[5] * inv), f2bf(e[6] * inv), f2bf(e[7] * inv) };
  ((u16x4*)prow)[t] = o0;
  ((u16x4*)prow)[256 + t] = o1;
}

// ---------- PV GEMM: out = P @ Vt^T ----------
__global__ __launch_bounds__(256, 4) void pv_kernel(
    const u16* __restrict__ P, const u16* __restrict__ vt, float* __restrict__ out)
{
  const int bx = blockIdx.x, by = blockIdx.y, b = blockIdx.z;
  f32x4 acc[4][4];
  gemm_core_plain(P + ((size_t)b * S_LEN + by * 128) * (2 * S_LEN),
                  vt + ((size_t)b * HDIM + bx * 128) * S_LEN,
                  2 * S_LEN, S_LEN, S_LEN, acc);
  const int lane = threadIdx.x & 63, wave = threadIdx.x >> 6;
  const int wm = wave >> 1, wn = wave & 1;
#pragma unroll
  for (int i = 0; i < 4; ++i) {
#pragma unroll
    for (int r = 0; r < 4; ++r) {
      const int q = by * 128 + wm * 64 + i * 16 + (lane >> 4) * 4 + r;
#pragma unroll
      for (int j = 0; j < 4; ++j) {
        const int h = bx * 128 + wn * 64 + j * 16 + (lane & 15);
        out[((size_t)b * S_LEN + q) * HDIM + h] = acc[i][j][r];
      }
    }
  }
}

extern "C" void kernel_launch(void* const* d_in, const int* in_sizes, int n_in,
                              void* d_out, int out_size, void* d_ws, size_t ws_size,
                              hipStream_t stream)
{
  const float* qkv  = (const float*)d_in[0];
  const void*  mask = d_in[1];
  const float* W    = (const float*)d_in[2];
  const float* bias = (const float*)d_in[3];
  float* out = (float*)d_out;
  char* ws = (char*)d_ws;

  const size_t off_mask = 0;
  const size_t off_Whi  = 32768;
  const size_t off_Wlo  = off_Whi + (size_t)N3H * DIN * 2;
  const size_t off_Qhi  = off_Wlo + (size_t)N3H * DIN * 2;
  const size_t off_Qlo  = off_Qhi + (size_t)NTOK * HDIM * 2;
  const size_t off_Khi  = off_Qlo + (size_t)NTOK * HDIM * 2;
  const size_t off_Klo  = off_Khi + (size_t)NTOK * HDIM * 2;
  const size_t off_Vt   = off_Klo + (size_t)NTOK * HDIM * 2;
  const size_t off_A    = off_Vt + (size_t)NTOK * HDIM * 2;
  const size_t off_Alo  = off_A + (size_t)NTOK * DIN * 2;
  const size_t off_sc   = off_A;  // scores (67MB) overlay A-split (dead after proj)
  // total ws requirement: off_A + BATCH*S*S*4 = ~156 MiB

  float* maskbias = (float*)(ws + off_mask);
  u16* Whi = (u16*)(ws + off_Whi);  u16* Wlo = (u16*)(ws + off_Wlo);
  u16* Qhi = (u16*)(ws + off_Qhi);  u16* Qlo = (u16*)(ws + off_Qlo);
  u16* Khi = (u16*)(ws + off_Khi);  u16* Klo = (u16*)(ws + off_Klo);
  u16* Vt  = (u16*)(ws + off_Vt);
  u16* Ahi = (u16*)(ws + off_A);    u16* Alo = (u16*)(ws + off_Alo);
  float* scores = (float*)(ws + off_sc);

  prep_mask_kernel<<<1, 256, 0, stream>>>((const unsigned char*)mask, maskbias);
  split_f32_kernel<<<NTOK * DIN / 1024, 256, 0, stream>>>(qkv, Ahi, Alo);
  splitWT_kernel<<<N3H * DIN / 256, 256, 0, stream>>>(W, Whi, Wlo);
  proj_qk_kernel<<<dim3(2 * HDIM / 128, NTOK / 128, 1), 256, 0, stream>>>(
      Ahi, Alo, Whi, Wlo, bias, Qhi, Qlo, Khi, Klo);
  proj_v_kernel<<<dim3(HDIM / 128, NTOK / 128, 1), 256, 0, stream>>>(
      Ahi, Whi, bias, Vt);
  scores_kernel<<<dim3(S_LEN / 128, S_LEN / 128, BATCH), 256, 0, stream>>>(
      Qhi, Qlo, Khi, Klo, maskbias, scores);
  softmax_kernel<<<NTOK, 256, 0, stream>>>(scores);
  pv_kernel<<<dim3(HDIM / 128, S_LEN / 128, BATCH), 256, 0, stream>>>(
      (const u16*)scores, Vt, out);
}

// Round 4
// 448.640 us; speedup vs baseline: 1.1229x; 1.1229x over previous
//
#include <hip/hip_runtime.h>
#include <stdint.h>

// Problem: B=4, S=2048, D_IN=1024, H=1024; fp32 in/out.
// Pipeline: [prep_mask] [split qkv->bf16 hi/lo] [split+transpose W]
//           [proj_qk GEMM split-bf16 -> Qhi/Qlo/Khi/Klo]
//           [proj_v GEMM plain bf16 -> Vt]
//           [scores GEMM split-bf16 *32 + maskbias -> fp32 scores]
//           [softmax in-place -> bf16 P]   [PV GEMM bf16 -> out]
// NOTE (R3 post-mortem): __launch_bounds__ min-waves MUST stay 2 for the GEMM
// kernels. 4 blocks/CU doubles the per-XCD L2 working set past 4 MiB ->
// FETCH 149->223MB, WRITE 99->421MB, MfmaUtil 35->23%. Cache locality > occupancy here.

#define S_LEN 2048
#define BATCH 4
#define DIN   1024
#define HDIM  1024
#define N3H   3072
#define NTOK  8192   // BATCH*S_LEN

typedef unsigned short u16;
typedef __attribute__((ext_vector_type(8))) short bf16x8;
typedef __attribute__((ext_vector_type(4))) float f32x4;
typedef __attribute__((ext_vector_type(4))) unsigned short u16x4;

// ---------- bf16 helpers (bit ops, RN) ----------
__device__ __forceinline__ u16 f2bf(float x) {
  union { float f; unsigned u; } c; c.f = x;
  unsigned r = c.u + 0x7fffu + ((c.u >> 16) & 1u);
  return (u16)(r >> 16);
}
__device__ __forceinline__ float bf2f(u16 h) {
  union { unsigned u; float f; } c; c.u = ((unsigned)h) << 16;
  return c.f;
}

// ---------- async global->LDS, width 16 ----------
__device__ __forceinline__ void gload16(const void* g, void* lds) {
  auto* gp = reinterpret_cast<const __attribute__((address_space(1))) void*>(
      reinterpret_cast<uintptr_t>(g));
  auto* lp = reinterpret_cast<__attribute__((address_space(3))) void*>(
      (unsigned)reinterpret_cast<uintptr_t>(lds));
  __builtin_amdgcn_global_load_lds(gp, lp, 16, 0, 0);
}

// Stage a 128x32 bf16 tile (row-major, row stride ld elems) into LDS (row-major [128][32]).
__device__ __forceinline__ void stage_tile(const u16* __restrict__ g, int ld,
                                           u16* lds, int wave, int lane) {
  const int rlane = lane >> 2;       // 0..15
  const int kofs  = (lane & 3) * 8;  // 0,8,16,24
#pragma unroll
  for (int h = 0; h < 2; ++h) {
    const int instr = wave * 2 + h;  // 0..7
    const u16* gp = g + (size_t)(instr * 16 + rlane) * ld + kofs;
    gload16(gp, (char*)lds + instr * 1024);
  }
}

// ---------- split-precision gemm_bt core: C(128x128) += (Ah+Al)*(Bh+Bl)^T ----------
// 3 MFMA products (hh, hl, lh); lo*lo dropped (2^-18 rel, negligible).
__device__ __forceinline__ void gemm_core_split(
    const u16* __restrict__ Ah, const u16* __restrict__ Al,
    const u16* __restrict__ Bh, const u16* __restrict__ Bl,
    int lda, int ldb, int K, f32x4 acc[4][4])
{
  __shared__ __align__(16) u16 lds[4 * 4096];  // aH | aL | bH | bL, 8KB each
  u16* aH = lds;          u16* aL = lds + 4096;
  u16* bH = lds + 8192;   u16* bL = lds + 12288;
  const int tid  = threadIdx.x;
  const int wave = tid >> 6, lane = tid & 63;
  const int wm = wave >> 1, wn = wave & 1;
  const int lrow = lane & 15, kq = lane >> 4;

  const f32x4 kZero = {0.f, 0.f, 0.f, 0.f};
#pragma unroll
  for (int i = 0; i < 4; ++i)
#pragma unroll
    for (int j = 0; j < 4; ++j) acc[i][j] = kZero;

  for (int k0 = 0; k0 < K; k0 += 32) {
    stage_tile(Ah + k0, lda, aH, wave, lane);
    stage_tile(Al + k0, lda, aL, wave, lane);
    stage_tile(Bh + k0, ldb, bH, wave, lane);
    stage_tile(Bl + k0, ldb, bL, wave, lane);
    __syncthreads();   // drains vmcnt (global_load_lds) before LDS reads

    bf16x8 fah[4], fal[4];
#pragma unroll
    for (int i = 0; i < 4; ++i) {
      const int off = (wm * 64 + i * 16 + lrow) * 32 + kq * 8;
      fah[i] = *(const bf16x8*)(aH + off);
      fal[i] = *(const bf16x8*)(aL + off);
    }
#pragma unroll
    for (int j = 0; j < 4; ++j) {
      const int off = (wn * 64 + j * 16 + lrow) * 32 + kq * 8;
      const bf16x8 fbh = *(const bf16x8*)(bH + off);
      const bf16x8 fbl = *(const bf16x8*)(bL + off);
#pragma unroll
      for (int i = 0; i < 4; ++i) {
        acc[i][j] = __builtin_amdgcn_mfma_f32_16x16x32_bf16(fah[i], fbh, acc[i][j], 0, 0, 0);
        acc[i][j] = __builtin_amdgcn_mfma_f32_16x16x32_bf16(fah[i], fbl, acc[i][j], 0, 0, 0);
        acc[i][j] = __builtin_amdgcn_mfma_f32_16x16x32_bf16(fal[i], fbh, acc[i][j], 0, 0, 0);
      }
    }
    __syncthreads();   // protect LDS before next stage
  }
}

// ---------- plain bf16 gemm_bt core ----------
__device__ __forceinline__ void gemm_core_plain(
    const u16* __restrict__ A, const u16* __restrict__ B,
    int lda, int ldb, int K, f32x4 acc[4][4])
{
  __shared__ __align__(16) u16 lds[2 * 4096];
  u16* aT = lds; u16* bT = lds + 4096;
  const int tid  = threadIdx.x;
  const int wave = tid >> 6, lane = tid & 63;
  const int wm = wave >> 1, wn = wave & 1;
  const int lrow = lane & 15, kq = lane >> 4;

  const f32x4 kZero = {0.f, 0.f, 0.f, 0.f};
#pragma unroll
  for (int i = 0; i < 4; ++i)
#pragma unroll
    for (int j = 0; j < 4; ++j) acc[i][j] = kZero;

  for (int k0 = 0; k0 < K; k0 += 32) {
    stage_tile(A + k0, lda, aT, wave, lane);
    stage_tile(B + k0, ldb, bT, wave, lane);
    __syncthreads();
    bf16x8 fa[4];
#pragma unroll
    for (int i = 0; i < 4; ++i) {
      const int off = (wm * 64 + i * 16 + lrow) * 32 + kq * 8;
      fa[i] = *(const bf16x8*)(aT + off);
    }
#pragma unroll
    for (int j = 0; j < 4; ++j) {
      const int off = (wn * 64 + j * 16 + lrow) * 32 + kq * 8;
      const bf16x8 fb = *(const bf16x8*)(bT + off);
#pragma unroll
      for (int i = 0; i < 4; ++i)
        acc[i][j] = __builtin_amdgcn_mfma_f32_16x16x32_bf16(fa[i], fb, acc[i][j], 0, 0, 0);
    }
    __syncthreads();
  }
}

// ---------- mask prep: detect bool(1B) vs int32(4B) repr, write additive bias ----------
__global__ void prep_mask_kernel(const unsigned char* __restrict__ m,
                                 float* __restrict__ bias) {
  __shared__ int isBool;
  if (threadIdx.x == 0) isBool = 0;
  __syncthreads();
  for (int i = threadIdx.x; i < NTOK; i += 256)
    if ((i & 3) && m[i]) isBool = 1;   // int32 repr of 0/1 has zero bytes at %4!=0
  __syncthreads();
  const int stride = isBool ? 1 : 4;
  const float ninf = -__builtin_inff();
  for (int i = threadIdx.x; i < NTOK; i += 256)
    bias[i] = m[(size_t)i * stride] ? ninf : 0.f;
}

// ---------- split fp32 -> bf16 hi/lo ----------
__global__ __launch_bounds__(256) void split_f32_kernel(
    const float* __restrict__ x, u16* __restrict__ hi, u16* __restrict__ lo) {
  const int i = (blockIdx.x * 256 + threadIdx.x) * 4;
  const f32x4 v = *(const f32x4*)(x + i);
  u16x4 h, l;
#pragma unroll
  for (int c = 0; c < 4; ++c) {
    h[c] = f2bf(v[c]);
    l[c] = f2bf(v[c] - bf2f(h[c]));
  }
  *(u16x4*)(hi + i) = h;
  *(u16x4*)(lo + i) = l;
}

// ---------- transpose + split W (DINxN3H -> N3HxDIN) ----------
__global__ __launch_bounds__(256) void splitWT_kernel(
    const float* __restrict__ W, u16* __restrict__ whi, u16* __restrict__ wlo) {
  const int o = blockIdx.x * 256 + threadIdx.x;  // o = n*DIN + d
  const int n = o >> 10, d = o & 1023;
  const float v = W[(size_t)d * N3H + n];
  const u16 h = f2bf(v);
  whi[o] = h;
  wlo[o] = f2bf(v - bf2f(h));
}

// ---------- projection GEMM (Q,K thirds): split precision ----------
__global__ __launch_bounds__(256, 2) void proj_qk_kernel(
    const u16* __restrict__ Ahi, const u16* __restrict__ Alo,
    const u16* __restrict__ Whi, const u16* __restrict__ Wlo,
    const float* __restrict__ bias,
    u16* __restrict__ qhi, u16* __restrict__ qlo,
    u16* __restrict__ khi, u16* __restrict__ klo)
{
  const int bx = blockIdx.x, by = blockIdx.y;  // bx over 16 tiles (cols 0..2047)
  f32x4 acc[4][4];
  gemm_core_split(Ahi + (size_t)by * 128 * DIN, Alo + (size_t)by * 128 * DIN,
                  Whi + (size_t)bx * 128 * DIN, Wlo + (size_t)bx * 128 * DIN,
                  DIN, DIN, DIN, acc);
  const int lane = threadIdx.x & 63, wave = threadIdx.x >> 6;
  const int wm = wave >> 1, wn = wave & 1;
#pragma unroll
  for (int i = 0; i < 4; ++i) {
#pragma unroll
    for (int r = 0; r < 4; ++r) {
      const int row = by * 128 + wm * 64 + i * 16 + (lane >> 4) * 4 + r;  // token
#pragma unroll
      for (int j = 0; j < 4; ++j) {
        const int col = bx * 128 + wn * 64 + j * 16 + (lane & 15);  // 0..2047
        const float v = acc[i][j][r] + bias[col];
        const u16 h = f2bf(v);
        const u16 l = f2bf(v - bf2f(h));
        if (col < HDIM) {                       // Q (block-uniform branch)
          const size_t idx = (size_t)row * HDIM + col;
          qhi[idx] = h; qlo[idx] = l;
        } else {                                // K
          const size_t idx = (size_t)row * HDIM + (col - HDIM);
          khi[idx] = h; klo[idx] = l;
        }
      }
    }
  }
}

// ---------- projection GEMM (V third): plain bf16, writes V transposed ----------
__global__ __launch_bounds__(256, 2) void proj_v_kernel(
    const u16* __restrict__ Ahi, const u16* __restrict__ Whi,
    const float* __restrict__ bias, u16* __restrict__ vt)
{
  const int bx = blockIdx.x, by = blockIdx.y;  // bx over 8 tiles (cols 2048..3071)
  f32x4 acc[4][4];
  gemm_core_plain(Ahi + (size_t)by * 128 * DIN,
                  Whi + (size_t)(2048 + bx * 128) * DIN,
                  DIN, DIN, DIN, acc);
  const int lane = threadIdx.x & 63, wave = threadIdx.x >> 6;
  const int wm = wave >> 1, wn = wave & 1;
#pragma unroll
  for (int i = 0; i < 4; ++i) {
#pragma unroll
    for (int r = 0; r < 4; ++r) {
      const int row = by * 128 + wm * 64 + i * 16 + (lane >> 4) * 4 + r;  // token
      const int b = row >> 11, s = row & 2047;
#pragma unroll
      for (int j = 0; j < 4; ++j) {
        const int hcol = bx * 128 + wn * 64 + j * 16 + (lane & 15);  // 0..1023
        const float v = acc[i][j][r] + bias[2 * HDIM + hcol];
        vt[((size_t)b * HDIM + hcol) * S_LEN + s] = f2bf(v);
      }
    }
  }
}

// ---------- scores GEMM: sc = 32 * Q @ K^T + maskbias(key) ----------
__global__ __launch_bounds__(256, 2) void scores_kernel(
    const u16* __restrict__ qhi, const u16* __restrict__ qlo,
    const u16* __restrict__ khi, const u16* __restrict__ klo,
    const float* __restrict__ maskbias, float* __restrict__ scores)
{
  const int bx = blockIdx.x, by = blockIdx.y, b = blockIdx.z;
  f32x4 acc[4][4];
  const size_t qoff = ((size_t)b * S_LEN + by * 128) * HDIM;
  const size_t koff = ((size_t)b * S_LEN + bx * 128) * HDIM;
  gemm_core_split(qhi + qoff, qlo + qoff, khi + koff, klo + koff,
                  HDIM, HDIM, HDIM, acc);
  const int lane = threadIdx.x & 63, wave = threadIdx.x >> 6;
  const int wm = wave >> 1, wn = wave & 1;
#pragma unroll
  for (int i = 0; i < 4; ++i) {
#pragma unroll
    for (int r = 0; r < 4; ++r) {
      const int q = by * 128 + wm * 64 + i * 16 + (lane >> 4) * 4 + r;
#pragma unroll
      for (int j = 0; j < 4; ++j) {
        const int key = bx * 128 + wn * 64 + j * 16 + (lane & 15);
        scores[((size_t)b * S_LEN + q) * S_LEN + key] =
            32.0f * acc[i][j][r] + maskbias[b * S_LEN + key];
      }
    }
  }
}

// ---------- block reductions ----------
__device__ __forceinline__ float block_reduce_max(float v) {
#pragma unroll
  for (int o = 32; o > 0; o >>= 1) v = fmaxf(v, __shfl_down(v, o));
  __shared__ float tmp[4]; __shared__ float res;
  if ((threadIdx.x & 63) == 0) tmp[threadIdx.x >> 6] = v;
  __syncthreads();
  if (threadIdx.x == 0) res = fmaxf(fmaxf(tmp[0], tmp[1]), fmaxf(tmp[2], tmp[3]));
  __syncthreads();
  return res;
}
__device__ __forceinline__ float block_reduce_sum(float v) {
#pragma unroll
  for (int o = 32; o > 0; o >>= 1) v += __shfl_down(v, o);
  __shared__ float tmp[4]; __shared__ float res;
  if ((threadIdx.x & 63) == 0) tmp[threadIdx.x >> 6] = v;
  __syncthreads();
  if (threadIdx.x == 0) res = tmp[0] + tmp[1] + tmp[2] + tmp[3];
  __syncthreads();
  return res;
}

// ---------- softmax, in-place fp32 row -> bf16 P (row stride stays 8KB) ----------
__global__ __launch_bounds__(256) void softmax_kernel(float* __restrict__ scores) {
  const int row = blockIdx.x;              // 0..NTOK-1
  float* srow = scores + (size_t)row * S_LEN;
  const int t = threadIdx.x;
  const f32x4 v0 = ((const f32x4*)srow)[t];        // elems 4t..4t+3
  const f32x4 v1 = ((const f32x4*)srow)[256 + t];  // elems 1024+4t..

  float m = fmaxf(fmaxf(v0[0], v0[1]), fmaxf(v0[2], v0[3]));
  m = fmaxf(m, fmaxf(fmaxf(v1[0], v1[1]), fmaxf(v1[2], v1[3])));
  const float rowmax = block_reduce_max(m);

  float e[8];
#pragma unroll
  for (int c = 0; c < 4; ++c) e[c]     = expf(v0[c] - rowmax);
#pragma unroll
  for (int c = 0; c < 4; ++c) e[4 + c] = expf(v1[c] - rowmax);
  float s = 0.f;
#pragma unroll
  for (int c = 0; c < 8; ++c) s += e[c];
  const float inv = 1.0f / block_reduce_sum(s);

  u16* prow = (u16*)srow;   // bf16 row at same base; valid elems 0..2047, stride 4096
  u16x4 o0 = { f2bf(e[0] * inv), f2bf(e[1] * inv), f2bf(e[2] * inv), f2bf(e[3] * inv) };
  u16x4 o1 = { f2bf(e[4] * inv), f2bf(e[5] * inv), f2bf(e[6] * inv), f2bf(e[7] * inv) };
  ((u16x4*)prow)[t] = o0;
  ((u16x4*)prow)[256 + t] = o1;
}

// ---------- PV GEMM: out = P @ Vt^T ----------
__global__ __launch_bounds__(256, 2) void pv_kernel(
    const u16* __restrict__ P, const u16* __restrict__ vt, float* __restrict__ out)
{
  const int bx = blockIdx.x, by = blockIdx.y, b = blockIdx.z;
  f32x4 acc[4][4];
  gemm_core_plain(P + ((size_t)b * S_LEN + by * 128) * (2 * S_LEN),
                  vt + ((size_t)b * HDIM + bx * 128) * S_LEN,
                  2 * S_LEN, S_LEN, S_LEN, acc);
  const int lane = threadIdx.x & 63, wave = threadIdx.x >> 6;
  const int wm = wave >> 1, wn = wave & 1;
#pragma unroll
  for (int i = 0; i < 4; ++i) {
#pragma unroll
    for (int r = 0; r < 4; ++r) {
      const int q = by * 128 + wm * 64 + i * 16 + (lane >> 4) * 4 + r;
#pragma unroll
      for (int j = 0; j < 4; ++j) {
        const int h = bx * 128 + wn * 64 + j * 16 + (lane & 15);
        out[((size_t)b * S_LEN + q) * HDIM + h] = acc[i][j][r];
      }
    }
  }
}

extern "C" void kernel_launch(void* const* d_in, const int* in_sizes, int n_in,
                              void* d_out, int out_size, void* d_ws, size_t ws_size,
                              hipStream_t stream)
{
  const float* qkv  = (const float*)d_in[0];
  const void*  mask = d_in[1];
  const float* W    = (const float*)d_in[2];
  const float* bias = (const float*)d_in[3];
  float* out = (float*)d_out;
  char* ws = (char*)d_ws;

  const size_t off_mask = 0;
  const size_t off_Whi  = 32768;
  const size_t off_Wlo  = off_Whi + (size_t)N3H * DIN * 2;
  const size_t off_Qhi  = off_Wlo + (size_t)N3H * DIN * 2;
  const size_t off_Qlo  = off_Qhi + (size_t)NTOK * HDIM * 2;
  const size_t off_Khi  = off_Qlo + (size_t)NTOK * HDIM * 2;
  const size_t off_Klo  = off_Khi + (size_t)NTOK * HDIM * 2;
  const size_t off_Vt   = off_Klo + (size_t)NTOK * HDIM * 2;
  const size_t off_A    = off_Vt + (size_t)NTOK * HDIM * 2;
  const size_t off_Alo  = off_A + (size_t)NTOK * DIN * 2;
  const size_t off_sc   = off_A;  // scores (67MB) overlay A-split (dead after proj)
  // total ws requirement: off_A + BATCH*S*S*4 = ~156 MiB

  float* maskbias = (float*)(ws + off_mask);
  u16* Whi = (u16*)(ws + off_Whi);  u16* Wlo = (u16*)(ws + off_Wlo);
  u16* Qhi = (u16*)(ws + off_Qhi);  u16* Qlo = (u16*)(ws + off_Qlo);
  u16* Khi = (u16*)(ws + off_Khi);  u16* Klo = (u16*)(ws + off_Klo);
  u16* Vt  = (u16*)(ws + off_Vt);
  u16* Ahi = (u16*)(ws + off_A);    u16* Alo = (u16*)(ws + off_Alo);
  float* scores = (float*)(ws + off_sc);

  prep_mask_kernel<<<1, 256, 0, stream>>>((const unsigned char*)mask, maskbias);
  split_f32_kernel<<<NTOK * DIN / 1024, 256, 0, stream>>>(qkv, Ahi, Alo);
  splitWT_kernel<<<N3H * DIN / 256, 256, 0, stream>>>(W, Whi, Wlo);
  proj_qk_kernel<<<dim3(2 * HDIM / 128, NTOK / 128, 1), 256, 0, stream>>>(
      Ahi, Alo, Whi, Wlo, bias, Qhi, Qlo, Khi, Klo);
  proj_v_kernel<<<dim3(HDIM / 128, NTOK / 128, 1), 256, 0, stream>>>(
      Ahi, Whi, bias, Vt);
  scores_kernel<<<dim3(S_LEN / 128, S_LEN / 128, BATCH), 256, 0, stream>>>(
      Qhi, Qlo, Khi, Klo, maskbias, scores);
  softmax_kernel<<<NTOK, 256, 0, stream>>>(scores);
  pv_kernel<<<dim3(HDIM / 128, S_LEN / 128, BATCH), 256, 0, stream>>>(
      (const u16*)scores, Vt, out);
}